// Round 8
// baseline (454.649 us; speedup 1.0000x reference)
//
#include <hip/hip_runtime.h>

// QORNN v8: dual-pipe hybrid. r7 evidence: replicated-A MFMA rate ==
// VALU-sdot rate (~100-128 ops/cy/SIMD) -> substitution was neutral (876cy
// step both). But MFMA and VALU pipes co-schedule (m114), so each wave now
// computes 32 of its 64 outputs on the matrix pipe (2 tiles x 4 chained
// k-MFMAs, v7-validated gather) and 32 on the VALU (lane k-split by g=l>>4
// on the SAME A-fragment h-reads, shfl_xor(16/32) integer butterflies).
// Both pipes overlap from one issue stream: compute ~400cy -> ~220cy.
// h-write collapses to one ds_write_b8/lane (lane l holds output w*64+l
// after g-select). u-prefetch (2 MFMA + 8 sdot) in the barrier shadow.

#define TSEQ 1024
#define IDIM 64
#define HDIM 256
#define ODIM 16

typedef int v4i __attribute__((ext_vector_type(4)));

__device__ __forceinline__ int sdot4i8(int a, int b, int c) {
#if __has_builtin(__builtin_amdgcn_sdot4)
    return __builtin_amdgcn_sdot4(a, b, c, false);
#else
    int r = c;
    r += ((a << 24) >> 24) * ((b << 24) >> 24);
    r += ((a << 16) >> 24) * ((b << 16) >> 24);
    r += ((a << 8)  >> 24) * ((b << 8)  >> 24);
    r += (a >> 24) * (b >> 24);
    return r;
#endif
}

__device__ __forceinline__ int qpack4(float4 f, float s, float lo, float hi) {
    int a = (int)fminf(fmaxf(rintf(f.x * s), lo), hi);
    int b = (int)fminf(fmaxf(rintf(f.y * s), lo), hi);
    int c = (int)fminf(fmaxf(rintf(f.z * s), lo), hi);
    int d = (int)fminf(fmaxf(rintf(f.w * s), lo), hi);
    return (a & 255) | ((b & 255) << 8) | ((c & 255) << 16) | ((d & 255) << 24);
}

__global__ __launch_bounds__(256, 1)
void qornn_kernel(const float* __restrict__ x, const float* __restrict__ Wi,
                  const float* __restrict__ Wr, const float* __restrict__ Wo,
                  const float* __restrict__ bias, float* __restrict__ out) {
    __shared__ alignas(16) int xlds[TSEQ * 16 + 16]; // whole row int8-packed (64KB+pad)
    __shared__ alignas(16) int wstage[8192];         // 32KB weight staging
    __shared__ alignas(16) int wo_lds[1024];         // Wo int8 resident
    __shared__ alignas(16) int hbuf[2][64];          // double-buffered h (256 int8)

    const int tid = threadIdx.x;
    const int brow = blockIdx.x;
    const int w = tid >> 6;        // wave 0..3 -> outputs w*64 .. w*64+63
    const int l = tid & 63;
    const int g = l >> 4;          // lane group = k-slot (A-frag) AND output band
    const int n = l & 15;          // col within 16-wide band

    // ---- stage Wi [256x64] -> int8 (scale 8) ----
    {
        const float4* wi4 = (const float4*)Wi;
        #pragma unroll
        for (int it = 0; it < 16; ++it) {
            int flat = it * 256 + tid;               // dwords 0..4095 (16/row)
            wstage[flat] = qpack4(wi4[flat], 8.0f, -8.0f, 7.0f);
        }
    }
    __syncthreads();
    // MFMA u B-frags (tiles 0,1 -> cols w*64+t*16+n) + VALU u weights
    v4i wiB[2], wiV[2];
    #pragma unroll
    for (int t4 = 0; t4 < 2; ++t4)
        wiB[t4] = *(const v4i*)(wstage + (w * 64 + t4 * 16 + n) * 16 + g * 4);
    #pragma unroll
    for (int i = 0; i < 2; ++i)      // VALU outputs o = w*64+32+i*16+n
        wiV[i] = *(const v4i*)(wstage + (w * 64 + 32 + i * 16 + n) * 16 + g * 4);
    __syncthreads();

    // ---- stage Wr [256x256] -> int8 in two 128-row halves; gather both paths ----
    v4i wrB[2][4];   // MFMA: tile t cols w*64+t*16+n, k-chunk j
    v4i wrV[2][4];   // VALU: output w*64+32+i*16+n, k slice j*64+g*16..+15
    {
        const float4* wr4 = (const float4*)Wr;
        #pragma unroll
        for (int half = 0; half < 2; ++half) {
            #pragma unroll
            for (int it = 0; it < 32; ++it) {
                int flat = it * 256 + tid;           // dwords 0..8191 (64/row)
                wstage[flat] = qpack4(wr4[half * 8192 + flat], 8.0f, -8.0f, 7.0f);
            }
            __syncthreads();
            if ((w >> 1) == half) {
                const int rl = (w & 1) * 64;         // local row base in this half
                #pragma unroll
                for (int t4 = 0; t4 < 2; ++t4)
                    #pragma unroll
                    for (int j = 0; j < 4; ++j)
                        wrB[t4][j] =
                            *(const v4i*)(wstage + (rl + t4 * 16 + n) * 64 + j * 16 + g * 4);
                #pragma unroll
                for (int i = 0; i < 2; ++i)
                    #pragma unroll
                    for (int j = 0; j < 4; ++j)
                        wrV[i][j] =
                            *(const v4i*)(wstage + (rl + 32 + i * 16 + n) * 64 + j * 16 + g * 4);
            }
            __syncthreads();
        }
    }

    // ---- stage Wo [16x256] -> int8, resident ----
    {
        const float4* wo4 = (const float4*)Wo;
        #pragma unroll
        for (int it = 0; it < 4; ++it) {
            int flat = it * 256 + tid;
            wo_lds[flat] = qpack4(wo4[flat], 8.0f, -8.0f, 7.0f);
        }
    }

    // ---- stage entire x row to LDS as int8 (scale 128); h0 = 0 ----
    {
        const float4* rowf4 = (const float4*)(x + (size_t)brow * (TSEQ * IDIM));
        #pragma unroll 8
        for (int it = 0; it < 64; ++it) {
            int flat = it * 256 + tid;
            xlds[flat] = qpack4(rowf4[flat], 128.0f, -128.0f, 127.0f);
        }
    }
    if (tid < 64) hbuf[0][tid] = 0;
    __syncthreads();

    const float bv128 = bias[tid] * 128.0f;          // exact pow2 fold (v6-verified)
    const v4i zero4 = {0, 0, 0, 0};

    // u for t=0 (x A-frag: lane's 16B slice at g*16)
    v4i accp0, accp1;
    int uV0, uV1;
    {
        const v4i xA = *(const v4i*)((const char*)xlds + g * 16);
        accp0 = __builtin_amdgcn_mfma_i32_16x16x64_i8(xA, wiB[0], zero4, 0, 0, 0);
        accp1 = __builtin_amdgcn_mfma_i32_16x16x64_i8(xA, wiB[1], zero4, 0, 0, 0);
        int s0 = sdot4i8(xA.x, wiV[0].x, 0);
        s0 = sdot4i8(xA.y, wiV[0].y, s0);
        s0 = sdot4i8(xA.z, wiV[0].z, s0);
        uV0 = sdot4i8(xA.w, wiV[0].w, s0);
        int s1 = sdot4i8(xA.x, wiV[1].x, 0);
        s1 = sdot4i8(xA.y, wiV[1].y, s1);
        s1 = sdot4i8(xA.z, wiV[1].z, s1);
        uV1 = sdot4i8(xA.w, wiV[1].w, s1);
    }

    // ---- main recurrence: 1024 steps, 1 barrier/step, both pipes busy ----
    #pragma unroll 2
    for (int t = 0; t < TSEQ; ++t) {
        // shared h ingest: A-fragment layout, 4 b128/wave
        const char* hsrc = (const char*)hbuf[t & 1];
        v4i hA[4];
        #pragma unroll
        for (int j = 0; j < 4; ++j)
            hA[j] = *(const v4i*)(hsrc + j * 64 + g * 16);

        // MFMA path: outputs w*64 + {0..31} (2 tiles, 4-chained k)
        v4i acc0 = accp0, acc1 = accp1;
        #pragma unroll
        for (int j = 0; j < 4; ++j) {
            acc0 = __builtin_amdgcn_mfma_i32_16x16x64_i8(hA[j], wrB[0][j], acc0, 0, 0, 0);
            acc1 = __builtin_amdgcn_mfma_i32_16x16x64_i8(hA[j], wrB[1][j], acc1, 0, 0, 0);
        }

        // VALU path: outputs w*64+32+{n, 16+n}; per-lane k-slice {j*64+g*16..+15}
        int p0a = uV0, p0b = 0, p1a = uV1, p1b = 0;
        #pragma unroll
        for (int j = 0; j < 2; ++j) {
            p0a = sdot4i8(hA[j].x, wrV[0][j].x, p0a);
            p0a = sdot4i8(hA[j].y, wrV[0][j].y, p0a);
            p0a = sdot4i8(hA[j].z, wrV[0][j].z, p0a);
            p0a = sdot4i8(hA[j].w, wrV[0][j].w, p0a);
            p1a = sdot4i8(hA[j].x, wrV[1][j].x, p1a);
            p1a = sdot4i8(hA[j].y, wrV[1][j].y, p1a);
            p1a = sdot4i8(hA[j].z, wrV[1][j].z, p1a);
            p1a = sdot4i8(hA[j].w, wrV[1][j].w, p1a);
        }
        #pragma unroll
        for (int j = 2; j < 4; ++j) {
            p0b = sdot4i8(hA[j].x, wrV[0][j].x, p0b);
            p0b = sdot4i8(hA[j].y, wrV[0][j].y, p0b);
            p0b = sdot4i8(hA[j].z, wrV[0][j].z, p0b);
            p0b = sdot4i8(hA[j].w, wrV[0][j].w, p0b);
            p1b = sdot4i8(hA[j].x, wrV[1][j].x, p1b);
            p1b = sdot4i8(hA[j].y, wrV[1][j].y, p1b);
            p1b = sdot4i8(hA[j].z, wrV[1][j].z, p1b);
            p1b = sdot4i8(hA[j].w, wrV[1][j].w, p1b);
        }
        int p0 = p0a + p0b;
        int p1 = p1a + p1b;
        // integer butterfly over the 4 g-lanes (exact)
        p0 += __shfl_xor(p0, 16);
        p1 += __shfl_xor(p1, 16);
        p0 += __shfl_xor(p0, 32);
        p1 += __shfl_xor(p1, 32);

        // lane l holds output o = w*64 + g*16 + n == tid: select its z
        const int zmf = (g == 0) ? acc0.x : acc1.x;   // g<2: MFMA bands
        const int zvl = (g == 2) ? p0 : p1;           // g>=2: VALU bands
        const int zz  = (g < 2) ? zmf : zvl;

        // exact modrelu + requantize (bit-identical to reference)
        const float zf = (float)zz;
        const float t1 = fmaf(fabsf(zf), 0.125f, bv128);
        const float t2 = fmaxf(t1, 0.0f);
        const float r  = rintf(t2);
        const int vpos = (int)fminf(r, 127.0f);
        const int vneg = -(int)fminf(r, 128.0f);
        int hv = (zz < 0) ? vneg : vpos;
        hv = (zz == 0) ? 0 : hv;

        ((signed char*)hbuf[(t + 1) & 1])[tid] = (signed char)hv;

        // barrier-shadow: u for t+1 (h-independent; pad covers t=1023)
        const v4i xA = *(const v4i*)((const char*)xlds + (t + 1) * 64 + g * 16);
        accp0 = __builtin_amdgcn_mfma_i32_16x16x64_i8(xA, wiB[0], zero4, 0, 0, 0);
        accp1 = __builtin_amdgcn_mfma_i32_16x16x64_i8(xA, wiB[1], zero4, 0, 0, 0);
        int s0 = sdot4i8(xA.x, wiV[0].x, 0);
        s0 = sdot4i8(xA.y, wiV[0].y, s0);
        s0 = sdot4i8(xA.z, wiV[0].z, s0);
        uV0 = sdot4i8(xA.w, wiV[0].w, s0);
        int s1 = sdot4i8(xA.x, wiV[1].x, 0);
        s1 = sdot4i8(xA.y, wiV[1].y, s1);
        s1 = sdot4i8(xA.z, wiV[1].z, s1);
        uV1 = sdot4i8(xA.w, wiV[1].w, s1);

        __syncthreads();
    }

    // ---- epilogue: out[b, o] = h_1024 . Wo_row(o) / 1024  (h_1024 in hbuf[0]) ----
    if (tid < ODIM) {
        const int4* wo = (const int4*)wo_lds;
        const int4* hl = (const int4*)hbuf[0];
        int a0 = 0, a1 = 0, a2 = 0, a3 = 0;
        #pragma unroll
        for (int i = 0; i < 16; ++i) {
            int4 w4 = wo[tid * 16 + i];
            int4 h4 = hl[i];
            a0 = sdot4i8(h4.x, w4.x, a0);
            a1 = sdot4i8(h4.y, w4.y, a1);
            a2 = sdot4i8(h4.z, w4.z, a2);
            a3 = sdot4i8(h4.w, w4.w, a3);
        }
        out[brow * ODIM + tid] = (float)((a0 + a1) + (a2 + a3)) * 0.0009765625f;
    }
}

extern "C" void kernel_launch(void* const* d_in, const int* in_sizes, int n_in,
                              void* d_out, int out_size, void* d_ws, size_t ws_size,
                              hipStream_t stream) {
    const float* x  = (const float*)d_in[0];   // [B, T, I]
    const float* Wi = (const float*)d_in[1];   // [H, I]
    const float* Wr = (const float*)d_in[2];   // [H, H]
    const float* Wo = (const float*)d_in[3];   // [O, H]
    const float* b  = (const float*)d_in[4];   // [H]
    float* out = (float*)d_out;                // [B, O]

    const int B = in_sizes[0] / (TSEQ * IDIM); // 256
    qornn_kernel<<<B, HDIM, 0, stream>>>(x, Wi, Wr, Wo, b, out);
}